// Round 10
// baseline (160.877 us; speedup 1.0000x reference)
//
#include <hip/hip_runtime.h>

#define NB   64
#define NT   256
#define NI   512
#define NO   512
#define NOBS 128
#define ETA  0.01f

typedef __attribute__((ext_vector_type(8))) short bf16x8;
typedef __attribute__((ext_vector_type(4))) float f32x4;

__device__ __forceinline__ unsigned short f2bf(float f) {
    unsigned int u = __float_as_uint(f);
    return (unsigned short)((u + 0x7fffu + ((u >> 16) & 1u)) >> 16); // RNE
}

// packed fp32x2 -> bf16x2 (RNE, same bits as f2bf); no builtin on gfx950
__device__ __forceinline__ unsigned cvtpk(float lo, float hi) {
    unsigned r;
    asm("v_cvt_pk_bf16_f32 %0, %1, %2" : "=v"(r) : "v"(lo), "v"(hi));
    return r;
}

// ---------------- K1: fused convert + LDS-tiled bf16 MFMA GEMM ----------------
// Round-4 proven staging (direct load->cvt->LDS) + A=B dedup (sub 0/2 stage A
// only, MFMA reads B-fragments from As -> bit-identical, -20% fetch) +
// round-4 dispatch map. ETA folded into Gh/Gd.
__global__ __launch_bounds__(256)
void k1_gemm(const float* __restrict__ Xf, const float* __restrict__ Wf,
             const int* __restrict__ obs,
             float* __restrict__ Gd, unsigned short* __restrict__ Gh,
             float* __restrict__ P0)
{
    __shared__ unsigned short As[128 * 64];
    __shared__ unsigned short Bs[128 * 64];
    __shared__ int obsS[128];

    const int tid  = threadIdx.x;
    const int lane = tid & 63;
    const int wv   = tid >> 6;
    const int l16  = lane & 15;
    const int quad = lane >> 4;

    const int b   = blockIdx.x & 63;   // same-batch blocks -> same XCD (r4 map)
    const int sub = blockIdx.x >> 6;   // 0..4

    if (tid < 128) obsS[tid] = obs[tid];
    __syncthreads();

    int bm = 0, bn = 0;
    if (sub < 3) {
        bm = (sub >= 1) ? 1 : 0;
        bn = (sub == 2) ? 1 : 0;
    } else {
        bm = sub - 3;
    }
    const bool sameAB = (sub == 0) || (sub == 2);   // A rows == B rows

    const int mrow = tid >> 3;
    const int ccol = tid & 7;
    const float* aP[4];
    const float* bP[4];
    int slotv[4];
#pragma unroll
    for (int it = 0; it < 4; ++it) {
        const int m = it * 32 + mrow;
        slotv[it] = m * 64 + ((ccol ^ (m & 7)) * 8);
        aP[it] = Xf + ((size_t)b * NT + bm * 128 + m) * NI + ccol * 8;
        bP[it] = (sub < 3)
                   ? Xf + ((size_t)b * NT + bn * 128 + m) * NI + ccol * 8
                   : Wf + ((size_t)b * NO + obsS[m]) * NI + ccol * 8;
    }

    const int wm = (wv >> 1) * 64;
    const int wn = (wv & 1) * 64;

    f32x4 acc[4][4] = {};

    for (int kb = 0; kb < NI / 64; ++kb) {
        __syncthreads();
#pragma unroll
        for (int it = 0; it < 4; ++it) {
            const float4 a0 = *(const float4*)(aP[it]);
            const float4 a1 = *(const float4*)(aP[it] + 4);
            uint4 ap;
            ap.x = cvtpk(a0.x, a0.y); ap.y = cvtpk(a0.z, a0.w);
            ap.z = cvtpk(a1.x, a1.y); ap.w = cvtpk(a1.z, a1.w);
            *(uint4*)&As[slotv[it]] = ap;
            aP[it] += 64;
            if (!sameAB) {
                const float4 b0 = *(const float4*)(bP[it]);
                const float4 b1 = *(const float4*)(bP[it] + 4);
                uint4 bp;
                bp.x = cvtpk(b0.x, b0.y); bp.y = cvtpk(b0.z, b0.w);
                bp.z = cvtpk(b1.x, b1.y); bp.w = cvtpk(b1.z, b1.w);
                *(uint4*)&Bs[slotv[it]] = bp;
            }
            bP[it] += 64;
        }
        __syncthreads();
        const unsigned short* Bsrc = sameAB ? As : Bs;
#pragma unroll
        for (int ks = 0; ks < 2; ++ks) {
            const int q = ks * 4 + quad;
            bf16x8 af[4], bfr[4];
#pragma unroll
            for (int mt = 0; mt < 4; ++mt) {
                const int m = wm + mt * 16 + l16;
                af[mt] = *(const bf16x8*)&As[m * 64 + ((q ^ (m & 7)) * 8)];
            }
#pragma unroll
            for (int nt = 0; nt < 4; ++nt) {
                const int n = wn + nt * 16 + l16;
                bfr[nt] = *(const bf16x8*)&Bsrc[n * 64 + ((q ^ (n & 7)) * 8)];
            }
#pragma unroll
            for (int mt = 0; mt < 4; ++mt)
#pragma unroll
                for (int nt = 0; nt < 4; ++nt)
                    acc[mt][nt] = __builtin_amdgcn_mfma_f32_16x16x32_bf16(
                        af[mt], bfr[nt], acc[mt][nt], 0, 0, 0);
        }
    }

    if (sub < 3) {
        unsigned short* GhB = Gh + ((size_t)b << 16);
        float* GdB = Gd + ((size_t)b << 12);
#pragma unroll
        for (int mt = 0; mt < 4; ++mt)
#pragma unroll
            for (int nt = 0; nt < 4; ++nt) {
                const int gcol = bn * 128 + wn + nt * 16 + l16;
#pragma unroll
                for (int r = 0; r < 4; ++r) {
                    const int grow = bm * 128 + wm + mt * 16 + quad * 4 + r;
                    const float v = ETA * acc[mt][nt][r];   // ETA folded here
                    GhB[(size_t)grow * 256 + gcol] = f2bf(v);
                    if ((grow >> 4) == (gcol >> 4))
                        GdB[((grow >> 4) << 8) + ((grow & 15) << 4) + (gcol & 15)] = v;
                }
            }
    } else {
        float* Pb = P0 + (size_t)b * NT * NOBS + (size_t)bm * 128 * NOBS;
#pragma unroll
        for (int mt = 0; mt < 4; ++mt)
#pragma unroll
            for (int nt = 0; nt < 4; ++nt)
#pragma unroll
                for (int r = 0; r < 4; ++r)
                    Pb[(size_t)(wm + mt * 16 + quad * 4 + r) * NOBS
                       + wn + nt * 16 + l16] = acc[mt][nt][r];
    }
}

// ---------------- K2: single-wave barrier-free MFMA blocked scan ----------------
// Round-9 post-mortem: the single-wave design is sound but VGPR_Count=104 <
// the ~190 live registers it needs (acc[16]=64 + Af=60 + scan bufs) ->
// compiler SPILLED the MFMA accumulators to scratch -> 98us with all pipes
// idle and scratch traffic inflating FETCH_SIZE. Fix: __launch_bounds__(64,1)
// (min 1 wave/EU) -> VGPR budget up to 512, no spill. Occupancy of 1 wave/SIMD
// is intentional: 512 one-wave blocks = 2 blocks/CU on distinct SIMDs, and the
// kernel is a latency design (zero __syncthreads, all state in registers).

#define LDROW(Q0, Q1, Q2, Q3, U1)                                          \
    {                                                                      \
        if ((U1) <= 14) {                                                  \
            if ((U1) <= 2)  Q0 = *(const f32x4*)(gdc + (U1) * 16);         \
            if ((U1) <= 6)  Q1 = *(const f32x4*)(gdc + (U1) * 16 + 4);     \
            if ((U1) <= 10) Q2 = *(const f32x4*)(gdc + (U1) * 16 + 8);     \
            Q3 = *(const f32x4*)(gdc + (U1) * 16 + 12);                    \
        }                                                                  \
    }

#define GV(Q0, Q1, Q2, Q3, V)                                              \
    ((V) < 4 ? (Q0)[(V) & 3] : (V) < 8 ? (Q1)[(V) & 3]                     \
             : (V) < 12 ? (Q2)[(V) & 3] : (Q3)[(V) & 3])

#define SCAN_STEP(U, C0, C1, C2, C3, N0, N1, N2, N3)                       \
    {                                                                      \
        LDROW(N0, N1, N2, N3, (U) + 2)                                     \
        const float y = __builtin_amdgcn_rcpf(1.f + __expf(-p[(U)]));      \
        ob[obOff + (size_t)((U) * NOBS)] = y;                              \
        _Pragma("unroll")                                                  \
        for (int v = (U) + 1; v < 16; ++v)                                 \
            p[v] = fmaf(y, GV(C0, C1, C2, C3, v), p[v]);                   \
        if ((U) & 1)                                                       \
            ybf2[((U) >> 1) * 16 + j] =                                    \
                (unsigned)f2bf(eprev) | ((unsigned)f2bf(y) << 16);         \
        else                                                               \
            eprev = y;                                                     \
    }

__global__ __launch_bounds__(64, 1)
void k2_scan(const float* __restrict__ Gd, const unsigned short* __restrict__ Gh,
             const float* __restrict__ P0, float* __restrict__ out)
{
    __shared__ float gdiag[16 * 16 * 16];      // 16 KB [c][u][v] fp32 (= ETA*G)
    __shared__ float preS[16 * 17];            // padded transpose buffer
    __shared__ unsigned int ybf2[8 * 16];      // current chunk's packed y pairs

    const int lane = threadIdx.x;              // one wave: tid == lane
    const int l16  = lane & 15;
    const int quad = lane >> 4;

    const int b  = blockIdx.x & 63;            // same-batch blocks -> same XCD
    const int jg = blockIdx.x >> 6;            // 0..7 col-groups of 16

    const float* Pb = P0 + (size_t)b * NT * NOBS + jg * 16;
    const unsigned short* GhB = Gh + ((size_t)b << 16);
    float* ob = out + (size_t)b * NT * NOBS + jg * 16;

    // stage all 16 fp32 diag tiles (wave-private; lgkmcnt ordering suffices)
    {
        const f32x4* gs = (const f32x4*)(Gd + ((size_t)b << 12));
#pragma unroll
        for (int i = 0; i < 16; ++i)
            ((f32x4*)gdiag)[i * 64 + lane] = gs[i * 64 + lane];
    }

    // all 16 pre tiles as C-fragments: acc[T][r] = pre[T*16 + quad*4+r][l16]
    f32x4 acc[16];
#pragma unroll
    for (int T = 0; T < 16; ++T)
#pragma unroll
        for (int r = 0; r < 4; ++r)
            acc[T][r] = Pb[(size_t)(T * 16 + quad * 4 + r) * NOBS + l16];

    union AB { bf16x8 v; unsigned int d[4]; };
    AB Af[16];

    // dump one 16x16 fp32 tile through LDS, then 16 lanes run the serial
    // sigmoid scan for chunk c (intra-wave: lgkmcnt wait only)
    auto scan_chunk = [&](const int c, const f32x4 a) {
#pragma unroll
        for (int r = 0; r < 4; ++r)
            preS[(quad * 4 + r) * 17 + l16] = a[r];
        asm volatile("s_waitcnt lgkmcnt(0)" ::: "memory");
        __builtin_amdgcn_sched_barrier(0);   // rule #18
        __builtin_amdgcn_s_setprio(1);
        if (lane < 16) {
            const int j = lane;
            const float* gdc = gdiag + (c << 8);
            const size_t obOff = (size_t)(c << 4) * NOBS + j;
            float p[16];
#pragma unroll
            for (int u = 0; u < 16; ++u) p[u] = preS[u * 17 + j];
            // 3 rotating row buffers, loads issued 2 steps ahead of use
            f32x4 Aq0, Aq1, Aq2, Aq3, Bq0, Bq1, Bq2, Bq3, Cq0, Cq1, Cq2, Cq3;
            LDROW(Aq0, Aq1, Aq2, Aq3, 0)
            LDROW(Bq0, Bq1, Bq2, Bq3, 1)
            float eprev = 0.f;
            SCAN_STEP(0,  Aq0, Aq1, Aq2, Aq3, Cq0, Cq1, Cq2, Cq3)
            SCAN_STEP(1,  Bq0, Bq1, Bq2, Bq3, Aq0, Aq1, Aq2, Aq3)
            SCAN_STEP(2,  Cq0, Cq1, Cq2, Cq3, Bq0, Bq1, Bq2, Bq3)
            SCAN_STEP(3,  Aq0, Aq1, Aq2, Aq3, Cq0, Cq1, Cq2, Cq3)
            SCAN_STEP(4,  Bq0, Bq1, Bq2, Bq3, Aq0, Aq1, Aq2, Aq3)
            SCAN_STEP(5,  Cq0, Cq1, Cq2, Cq3, Bq0, Bq1, Bq2, Bq3)
            SCAN_STEP(6,  Aq0, Aq1, Aq2, Aq3, Cq0, Cq1, Cq2, Cq3)
            SCAN_STEP(7,  Bq0, Bq1, Bq2, Bq3, Aq0, Aq1, Aq2, Aq3)
            SCAN_STEP(8,  Cq0, Cq1, Cq2, Cq3, Bq0, Bq1, Bq2, Bq3)
            SCAN_STEP(9,  Aq0, Aq1, Aq2, Aq3, Cq0, Cq1, Cq2, Cq3)
            SCAN_STEP(10, Bq0, Bq1, Bq2, Bq3, Aq0, Aq1, Aq2, Aq3)
            SCAN_STEP(11, Cq0, Cq1, Cq2, Cq3, Bq0, Bq1, Bq2, Bq3)
            SCAN_STEP(12, Aq0, Aq1, Aq2, Aq3, Cq0, Cq1, Cq2, Cq3)
            SCAN_STEP(13, Bq0, Bq1, Bq2, Bq3, Aq0, Aq1, Aq2, Aq3)
            SCAN_STEP(14, Cq0, Cq1, Cq2, Cq3, Bq0, Bq1, Bq2, Bq3)
            SCAN_STEP(15, Aq0, Aq1, Aq2, Aq3, Cq0, Cq1, Cq2, Cq3)
        }
        __builtin_amdgcn_s_setprio(0);
    };

#pragma unroll
    for (int c = 0; c < 16; ++c) {
        // prefetch A(T, c) fragments for this chunk's updates; loads fly
        // during the scan below (consumed ~640cy later)
#pragma unroll
        for (int T = c + 1; T < 16; ++T) {
#pragma unroll
            for (int p2 = 0; p2 < 4; ++p2) Af[T].d[p2] = 0;
            if (quad < 2)
                Af[T].v = *(const bf16x8*)(GhB + (size_t)(T * 16 + l16) * 256
                                           + c * 16 + quad * 8);
        }
        scan_chunk(c, acc[c]);
        if (c < 15) {
            // B fragment from ybf2: B[k=u][n=j], upper K-half zero
            AB B;
#pragma unroll
            for (int p2 = 0; p2 < 4; ++p2) B.d[p2] = 0;
            if (quad < 2) {
#pragma unroll
                for (int p2 = 0; p2 < 4; ++p2)
                    B.d[p2] = ybf2[(quad * 4 + p2) * 16 + l16];
            }
            // eager rank-16 update of all future tiles (only T=c+1 is on the
            // critical path; the rest overlap the next scan's VALU work)
#pragma unroll
            for (int T = c + 1; T < 16; ++T)
                acc[T] = __builtin_amdgcn_mfma_f32_16x16x32_bf16(
                    Af[T].v, B.v, acc[T], 0, 0, 0);
        }
    }
}

extern "C" void kernel_launch(void* const* d_in, const int* in_sizes, int n_in,
                              void* d_out, int out_size, void* d_ws, size_t ws_size,
                              hipStream_t stream)
{
    const float* X   = (const float*)d_in[0];
    const float* Wi  = (const float*)d_in[1];
    const int*   obs = (const int*)d_in[2];
    float*       out = (float*)d_out;

    float*          Gd = (float*)d_ws;                                  //  1 MB
    float*          P0 = (float*)((char*)d_ws + (1u << 20));            //  8 MB
    unsigned short* Gh = (unsigned short*)((char*)d_ws + (9u << 20));   //  8 MB

    hipLaunchKernelGGL(k1_gemm, dim3(NB * 5), dim3(256), 0, stream,
                       X, Wi, obs, Gd, Gh, P0);
    hipLaunchKernelGGL(k2_scan, dim3(NB * 8), dim3(64), 0, stream,
                       Gd, Gh, P0, out);
}

// Round 11
// 157.363 us; speedup vs baseline: 1.0223x; 1.0223x over previous
//
#include <hip/hip_runtime.h>

#define NB   64
#define NT   256
#define NI   512
#define NO   512
#define NOBS 128
#define ETA  0.01f

typedef __attribute__((ext_vector_type(8))) short bf16x8;
typedef __attribute__((ext_vector_type(4))) float f32x4;

__device__ __forceinline__ unsigned short f2bf(float f) {
    unsigned int u = __float_as_uint(f);
    return (unsigned short)((u + 0x7fffu + ((u >> 16) & 1u)) >> 16); // RNE
}

// packed fp32x2 -> bf16x2 (RNE, same bits as f2bf); no builtin on gfx950
__device__ __forceinline__ unsigned cvtpk(float lo, float hi) {
    unsigned r;
    asm("v_cvt_pk_bf16_f32 %0, %1, %2" : "=v"(r) : "v"(lo), "v"(hi));
    return r;
}

// ---------------- K1: fused convert + LDS-tiled bf16 MFMA GEMM ----------------
// Round-10 post-mortem: conditional B-staging (dedup) cost +14us (load
// serialization); 320 blocks on 256 CUs -> wall = 2x block time. Round-11:
// 4 blocks/batch = 256 blocks = EXACTLY 1/CU, staging always stages TWO tiles
// unconditionally (r4's proven pattern):
//   sub0: A=rb0, B=W     -> G(0,0) (B-frags from As) AND P0 rows 0-127
//   sub1: A=rb1, B=rb0   -> G(1,0)
//   sub2: A=rb1, B=rb1   -> G(1,1) (dup stage keeps staging uniform)
//   sub3: A=rb1, B=W     -> P0 rows 128-255
// ETA folded into Gh/Gd (k2's scan uses e = y directly).
__global__ __launch_bounds__(256, 1)
void k1_gemm(const float* __restrict__ Xf, const float* __restrict__ Wf,
             const int* __restrict__ obs,
             float* __restrict__ Gd, unsigned short* __restrict__ Gh,
             float* __restrict__ P0)
{
    __shared__ unsigned short As[128 * 64];
    __shared__ unsigned short Bs[128 * 64];
    __shared__ int obsS[128];

    const int tid  = threadIdx.x;
    const int lane = tid & 63;
    const int wv   = tid >> 6;
    const int l16  = lane & 15;
    const int quad = lane >> 4;

    const int b   = blockIdx.x & 63;   // same-batch blocks -> same XCD (r4 map)
    const int sub = blockIdx.x >> 6;   // 0..3

    if (tid < 128) obsS[tid] = obs[tid];
    __syncthreads();

    const bool doG = (sub <= 2);
    const bool doP = (sub == 0) || (sub == 3);
    const int  bm  = (sub >= 1) ? 1 : 0;       // G row-block / A row-block
    const int  bn  = (sub == 2) ? 1 : 0;       // G col-block
    const int  pb  = (sub == 3) ? 1 : 0;       // P0 row-block
    const bool bw  = !doG || (sub == 0);       // B slot holds W rows?

    const int mrow = tid >> 3;
    const int ccol = tid & 7;
    const float* aP[4];
    const float* bP[4];
    int slotv[4];
#pragma unroll
    for (int it = 0; it < 4; ++it) {
        const int m = it * 32 + mrow;
        slotv[it] = m * 64 + ((ccol ^ (m & 7)) * 8);
        aP[it] = Xf + ((size_t)b * NT + bm * 128 + m) * NI + ccol * 8;
        bP[it] = bw
                   ? Wf + ((size_t)b * NO + obsS[m]) * NI + ccol * 8
                   : Xf + ((size_t)b * NT + ((sub == 2) ? 128 : 0) + m) * NI
                       + ccol * 8;
    }

    const int wm = (wv >> 1) * 64;
    const int wn = (wv & 1) * 64;

    f32x4 accG[4][4] = {};
    f32x4 accP[4][4] = {};

    for (int kb = 0; kb < NI / 64; ++kb) {
        __syncthreads();
#pragma unroll
        for (int it = 0; it < 4; ++it) {
            const float4 a0 = *(const float4*)(aP[it]);
            const float4 a1 = *(const float4*)(aP[it] + 4);
            const float4 b0 = *(const float4*)(bP[it]);
            const float4 b1 = *(const float4*)(bP[it] + 4);
            uint4 ap, bp;
            ap.x = cvtpk(a0.x, a0.y); ap.y = cvtpk(a0.z, a0.w);
            ap.z = cvtpk(a1.x, a1.y); ap.w = cvtpk(a1.z, a1.w);
            bp.x = cvtpk(b0.x, b0.y); bp.y = cvtpk(b0.z, b0.w);
            bp.z = cvtpk(b1.x, b1.y); bp.w = cvtpk(b1.z, b1.w);
            *(uint4*)&As[slotv[it]] = ap;
            *(uint4*)&Bs[slotv[it]] = bp;
            aP[it] += 64;
            bP[it] += 64;
        }
        __syncthreads();
        const unsigned short* BsrcG = (sub == 0) ? As : Bs;
#pragma unroll
        for (int ks = 0; ks < 2; ++ks) {
            const int q = ks * 4 + quad;
            bf16x8 af[4];
#pragma unroll
            for (int mt = 0; mt < 4; ++mt) {
                const int m = wm + mt * 16 + l16;
                af[mt] = *(const bf16x8*)&As[m * 64 + ((q ^ (m & 7)) * 8)];
            }
            if (doG) {
                bf16x8 bfr[4];
#pragma unroll
                for (int nt = 0; nt < 4; ++nt) {
                    const int n = wn + nt * 16 + l16;
                    bfr[nt] = *(const bf16x8*)&BsrcG[n * 64 + ((q ^ (n & 7)) * 8)];
                }
#pragma unroll
                for (int mt = 0; mt < 4; ++mt)
#pragma unroll
                    for (int nt = 0; nt < 4; ++nt)
                        accG[mt][nt] = __builtin_amdgcn_mfma_f32_16x16x32_bf16(
                            af[mt], bfr[nt], accG[mt][nt], 0, 0, 0);
            }
            if (doP) {
                bf16x8 bfr[4];
#pragma unroll
                for (int nt = 0; nt < 4; ++nt) {
                    const int n = wn + nt * 16 + l16;
                    bfr[nt] = *(const bf16x8*)&Bs[n * 64 + ((q ^ (n & 7)) * 8)];
                }
#pragma unroll
                for (int mt = 0; mt < 4; ++mt)
#pragma unroll
                    for (int nt = 0; nt < 4; ++nt)
                        accP[mt][nt] = __builtin_amdgcn_mfma_f32_16x16x32_bf16(
                            af[mt], bfr[nt], accP[mt][nt], 0, 0, 0);
            }
        }
    }

    if (doG) {
        unsigned short* GhB = Gh + ((size_t)b << 16);
        float* GdB = Gd + ((size_t)b << 12);
#pragma unroll
        for (int mt = 0; mt < 4; ++mt)
#pragma unroll
            for (int nt = 0; nt < 4; ++nt) {
                const int gcol = bn * 128 + wn + nt * 16 + l16;
#pragma unroll
                for (int r = 0; r < 4; ++r) {
                    const int grow = bm * 128 + wm + mt * 16 + quad * 4 + r;
                    const float v = ETA * accG[mt][nt][r];   // ETA folded here
                    GhB[(size_t)grow * 256 + gcol] = f2bf(v);
                    if ((grow >> 4) == (gcol >> 4))
                        GdB[((grow >> 4) << 8) + ((grow & 15) << 4) + (gcol & 15)] = v;
                }
            }
    }
    if (doP) {
        float* Pb = P0 + (size_t)b * NT * NOBS + (size_t)pb * 128 * NOBS;
#pragma unroll
        for (int mt = 0; mt < 4; ++mt)
#pragma unroll
            for (int nt = 0; nt < 4; ++nt)
#pragma unroll
                for (int r = 0; r < 4; ++r)
                    Pb[(size_t)(wm + mt * 16 + quad * 4 + r) * NOBS
                       + wn + nt * 16 + l16] = accP[mt][nt][r];
    }
}

// ---------------- K2: latency-optimized MFMA blocked scan ----------------
// BYTE-IDENTICAL to the round-7/8 version that passed twice (~38us).
// block = (b, 16 j's) -> 512 blocks (2/CU), 512 threads (8 waves).
// Serial scan runs with G rows software-pipelined 2 steps ahead into 3
// rotating register row-buffers. ETA pre-folded into G (k1).

#define LDROW(Q0, Q1, Q2, Q3, U1)                                          \
    {                                                                      \
        if ((U1) <= 14) {                                                  \
            if ((U1) <= 2)  Q0 = *(const f32x4*)(gdc + (U1) * 16);         \
            if ((U1) <= 6)  Q1 = *(const f32x4*)(gdc + (U1) * 16 + 4);     \
            if ((U1) <= 10) Q2 = *(const f32x4*)(gdc + (U1) * 16 + 8);     \
            Q3 = *(const f32x4*)(gdc + (U1) * 16 + 12);                    \
        }                                                                  \
    }

#define GV(Q0, Q1, Q2, Q3, V)                                              \
    ((V) < 4 ? (Q0)[(V) & 3] : (V) < 8 ? (Q1)[(V) & 3]                     \
             : (V) < 12 ? (Q2)[(V) & 3] : (Q3)[(V) & 3])

#define SCAN_STEP(U, C0, C1, C2, C3, N0, N1, N2, N3)                       \
    {                                                                      \
        LDROW(N0, N1, N2, N3, (U) + 2)                                     \
        const float y = __builtin_amdgcn_rcpf(1.f + __expf(-p[(U)]));      \
        ob[obOff + (size_t)((U) * NOBS)] = y;                              \
        _Pragma("unroll")                                                  \
        for (int v = (U) + 1; v < 16; ++v)                                 \
            p[v] = fmaf(y, GV(C0, C1, C2, C3, v), p[v]);                   \
        if ((U) & 1)                                                       \
            ybf2[cp * 128 + ((U) >> 1) * 16 + j] =                         \
                (unsigned)f2bf(eprev) | ((unsigned)f2bf(y) << 16);         \
        else                                                               \
            eprev = y;                                                     \
    }

__global__ __launch_bounds__(512, 4)
void k2_scan(const float* __restrict__ Gd, const unsigned short* __restrict__ Gh,
             const float* __restrict__ P0, float* __restrict__ out)
{
    __shared__ float gdiag[16 * 16 * 16];      // 16 KB [c][u][v] fp32 (= ETA*G)
    __shared__ float preS[16 * 17];            // padded transpose buffer
    __shared__ unsigned int ybf2[2 * 8 * 16];  // ping-pong packed y pairs

    const int tid  = threadIdx.x;
    const int lane = tid & 63;
    const int l16  = lane & 15;
    const int quad = lane >> 4;
    const int w    = __builtin_amdgcn_readfirstlane(tid >> 6);

    const int b  = blockIdx.x & 63;            // same-batch blocks -> same XCD
    const int jg = blockIdx.x >> 6;            // 0..7 col-groups of 16

    const float* Pb = P0 + (size_t)b * NT * NOBS + jg * 16;
    const unsigned short* GhB = Gh + ((size_t)b << 16);
    float* ob = out + (size_t)b * NT * NOBS + jg * 16;

    // stage fp32 diag tiles (Gd[b] is 16 KB contiguous).
    {
        const f32x4* gs = (const f32x4*)(Gd + ((size_t)b << 12));
        ((f32x4*)gdiag)[tid]       = gs[tid];
        ((f32x4*)gdiag)[512 + tid] = gs[512 + tid];
    }

    // init pre C-fragments from P0: D[m=quad*4+r][n=l16]
    f32x4 acc[2];
#pragma unroll
    for (int s2 = 0; s2 < 2; ++s2)
#pragma unroll
        for (int r = 0; r < 4; ++r)
            acc[s2][r] = Pb[(size_t)(w * 32 + s2 * 16 + quad * 4 + r) * NOBS + l16];

    const int T0 = 2 * w, T1 = 2 * w + 1;

    union AB { bf16x8 v; unsigned int d[4]; };
    AB Acur0, Acur1, Anext0, Anext1;
#pragma unroll
    for (int p2 = 0; p2 < 4; ++p2) {
        Acur0.d[p2] = 0; Acur1.d[p2] = 0; Anext0.d[p2] = 0; Anext1.d[p2] = 0;
    }
    // prefetch A(T, c=0)
    if (quad < 2) {
        if (T0 > 0)
            Acur0.v = *(const bf16x8*)(GhB + (size_t)(T0 * 16 + l16) * 256 + quad * 8);
        Acur1.v = *(const bf16x8*)(GhB + (size_t)(T1 * 16 + l16) * 256 + quad * 8);
    }

    // dump one 16x16 fp32 tile through LDS, then 16 lanes run the serial
    // sigmoid scan for chunk c (intra-wave only: lgkmcnt wait, no barrier)
    auto scan_chunk = [&](const int c, const f32x4 a) {
#pragma unroll
        for (int r = 0; r < 4; ++r)
            preS[(quad * 4 + r) * 17 + l16] = a[r];
        asm volatile("s_waitcnt lgkmcnt(0)" ::: "memory");
        __builtin_amdgcn_s_setprio(1);
        if (lane < 16) {
            const int j = lane;
            const int cp = c & 1;
            const float* gdc = gdiag + (c << 8);
            const size_t obOff = (size_t)(c << 4) * NOBS + j;
            float p[16];
#pragma unroll
            for (int u = 0; u < 16; ++u) p[u] = preS[u * 17 + j];
            // 3 rotating row buffers, loads issued 2 steps ahead of use
            f32x4 Aq0, Aq1, Aq2, Aq3, Bq0, Bq1, Bq2, Bq3, Cq0, Cq1, Cq2, Cq3;
            LDROW(Aq0, Aq1, Aq2, Aq3, 0)
            LDROW(Bq0, Bq1, Bq2, Bq3, 1)
            float eprev = 0.f;
            SCAN_STEP(0,  Aq0, Aq1, Aq2, Aq3, Cq0, Cq1, Cq2, Cq3)
            SCAN_STEP(1,  Bq0, Bq1, Bq2, Bq3, Aq0, Aq1, Aq2, Aq3)
            SCAN_STEP(2,  Cq0, Cq1, Cq2, Cq3, Bq0, Bq1, Bq2, Bq3)
            SCAN_STEP(3,  Aq0, Aq1, Aq2, Aq3, Cq0, Cq1, Cq2, Cq3)
            SCAN_STEP(4,  Bq0, Bq1, Bq2, Bq3, Aq0, Aq1, Aq2, Aq3)
            SCAN_STEP(5,  Cq0, Cq1, Cq2, Cq3, Bq0, Bq1, Bq2, Bq3)
            SCAN_STEP(6,  Aq0, Aq1, Aq2, Aq3, Cq0, Cq1, Cq2, Cq3)
            SCAN_STEP(7,  Bq0, Bq1, Bq2, Bq3, Aq0, Aq1, Aq2, Aq3)
            SCAN_STEP(8,  Cq0, Cq1, Cq2, Cq3, Bq0, Bq1, Bq2, Bq3)
            SCAN_STEP(9,  Aq0, Aq1, Aq2, Aq3, Cq0, Cq1, Cq2, Cq3)
            SCAN_STEP(10, Bq0, Bq1, Bq2, Bq3, Aq0, Aq1, Aq2, Aq3)
            SCAN_STEP(11, Cq0, Cq1, Cq2, Cq3, Bq0, Bq1, Bq2, Bq3)
            SCAN_STEP(12, Aq0, Aq1, Aq2, Aq3, Cq0, Cq1, Cq2, Cq3)
            SCAN_STEP(13, Bq0, Bq1, Bq2, Bq3, Aq0, Aq1, Aq2, Aq3)
            SCAN_STEP(14, Cq0, Cq1, Cq2, Cq3, Bq0, Bq1, Bq2, Bq3)
            SCAN_STEP(15, Aq0, Aq1, Aq2, Aq3, Cq0, Cq1, Cq2, Cq3)
        }
        __builtin_amdgcn_s_setprio(0);
    };

    // chunk 0: owner = wave 0 (tile 0 is P0-only, no updates needed)
    if (w == 0)
        scan_chunk(0, acc[0]);
    __syncthreads();

#pragma unroll 1
    for (int c = 0; c < 15; ++c) {
        if (T1 > c) {   // wave still has live tiles
            // B fragment from ybf2[c&1]: B[k=u][n=j], upper K-half zero
            AB B;
#pragma unroll
            for (int p2 = 0; p2 < 4; ++p2) B.d[p2] = 0;
            if (quad < 2) {
#pragma unroll
                for (int p2 = 0; p2 < 4; ++p2)
                    B.d[p2] = ybf2[(c & 1) * 128 + (quad * 4 + p2) * 16 + l16];
            }
            // prefetch A(T, c+1) for next iteration (covered by MFMA+scan)
#pragma unroll
            for (int p2 = 0; p2 < 4; ++p2) { Anext0.d[p2] = 0; Anext1.d[p2] = 0; }
            if (quad < 2) {
                if (T0 > c + 1)
                    Anext0.v = *(const bf16x8*)(GhB + (size_t)(T0 * 16 + l16) * 256
                                                + (c + 1) * 16 + quad * 8);
                if (T1 > c + 1)
                    Anext1.v = *(const bf16x8*)(GhB + (size_t)(T1 * 16 + l16) * 256
                                                + (c + 1) * 16 + quad * 8);
            }
            // rank-16 updates of this wave's future tiles
            if (T0 > c)
                acc[0] = __builtin_amdgcn_mfma_f32_16x16x32_bf16(
                    Acur0.v, B.v, acc[0], 0, 0, 0);
            acc[1] = __builtin_amdgcn_mfma_f32_16x16x32_bf16(
                Acur1.v, B.v, acc[1], 0, 0, 0);
            // owner of chunk c+1 scans it now (its own tile is fully updated),
            // overlapping the other waves' update work until the barrier.
            if (w == ((c + 1) >> 1)) {
                if ((c + 1) & 1) scan_chunk(c + 1, acc[1]);
                else             scan_chunk(c + 1, acc[0]);
            }
            Acur0 = Anext0;
            Acur1 = Anext1;
        }
        __syncthreads();
    }
}

extern "C" void kernel_launch(void* const* d_in, const int* in_sizes, int n_in,
                              void* d_out, int out_size, void* d_ws, size_t ws_size,
                              hipStream_t stream)
{
    const float* X   = (const float*)d_in[0];
    const float* Wi  = (const float*)d_in[1];
    const int*   obs = (const int*)d_in[2];
    float*       out = (float*)d_out;

    float*          Gd = (float*)d_ws;                                  //  1 MB
    float*          P0 = (float*)((char*)d_ws + (1u << 20));            //  8 MB
    unsigned short* Gh = (unsigned short*)((char*)d_ws + (9u << 20));   //  8 MB

    hipLaunchKernelGGL(k1_gemm, dim3(NB * 4), dim3(256), 0, stream,
                       X, Wi, obs, Gd, Gh, P0);
    hipLaunchKernelGGL(k2_scan, dim3(NB * 8), dim3(512), 0, stream,
                       Gd, Gh, P0, out);
}

// Round 12
// 148.767 us; speedup vs baseline: 1.0814x; 1.0578x over previous
//
#include <hip/hip_runtime.h>

#define NB   64
#define NT   256
#define NI   512
#define NO   512
#define NOBS 128
#define ETA  0.01f

typedef __attribute__((ext_vector_type(8))) short bf16x8;
typedef __attribute__((ext_vector_type(4))) float f32x4;

__device__ __forceinline__ unsigned short f2bf(float f) {
    unsigned int u = __float_as_uint(f);
    return (unsigned short)((u + 0x7fffu + ((u >> 16) & 1u)) >> 16); // RNE
}

// packed fp32x2 -> bf16x2 (RNE, same bits as f2bf); no builtin on gfx950
__device__ __forceinline__ unsigned cvtpk(float lo, float hi) {
    unsigned r;
    asm("v_cvt_pk_bf16_f32 %0, %1, %2" : "=v"(r) : "v"(lo), "v"(hi));
    return r;
}

// ---------------- K1: fused convert + LDS-tiled bf16 MFMA GEMM ----------------
// EXACT round-4 restoration (measured 146.6us total; k1 ~27us). All later k1
// variants regressed: A=B dedup +14us (conditional staging serialized loads),
// reg double-buffer +6us (VGPR 84->200 halved blocks/CU), batch-packed remap
// neutral-to-negative, 4-block rebalance +10us (sub0 straggler). Staging reads
// fp32 X / gathered fp32 Wi rows and converts to bf16 via v_cvt_pk_bf16_f32
// while writing LDS. 5 blocks/batch: sub 0->(0,0) 1->(1,0) 2->(1,1) of G
// (writes bf16 Gh + fp32 Gd diag tiles); sub 3..4 -> P0 row-blocks (fp32).
// ETA folded into Gh/Gd (k2's scan uses e = y directly).
__global__ __launch_bounds__(256)
void k1_gemm(const float* __restrict__ Xf, const float* __restrict__ Wf,
             const int* __restrict__ obs,
             float* __restrict__ Gd, unsigned short* __restrict__ Gh,
             float* __restrict__ P0)
{
    __shared__ unsigned short As[128 * 64];
    __shared__ unsigned short Bs[128 * 64];
    __shared__ int obsS[128];

    const int tid  = threadIdx.x;
    const int lane = tid & 63;
    const int wv   = tid >> 6;
    const int l16  = lane & 15;
    const int quad = lane >> 4;

    const int b   = blockIdx.x & 63;   // same-batch blocks -> same XCD
    const int sub = blockIdx.x >> 6;   // 0..4

    if (tid < 128) obsS[tid] = obs[tid];
    __syncthreads();

    int bm = 0, bn = 0;
    if (sub < 3) {
        bm = (sub >= 1) ? 1 : 0;
        bn = (sub == 2) ? 1 : 0;
    } else {
        bm = sub - 3;
    }

    const int mrow = tid >> 3;
    const int ccol = tid & 7;
    const float* aP[4];
    const float* bP[4];
    int slotv[4];
#pragma unroll
    for (int it = 0; it < 4; ++it) {
        const int m = it * 32 + mrow;
        slotv[it] = m * 64 + ((ccol ^ (m & 7)) * 8);
        aP[it] = Xf + ((size_t)b * NT + bm * 128 + m) * NI + ccol * 8;
        bP[it] = (sub < 3)
                   ? Xf + ((size_t)b * NT + bn * 128 + m) * NI + ccol * 8
                   : Wf + ((size_t)b * NO + obsS[m]) * NI + ccol * 8;
    }

    const int wm = (wv >> 1) * 64;
    const int wn = (wv & 1) * 64;

    f32x4 acc[4][4] = {};

    for (int kb = 0; kb < NI / 64; ++kb) {
        __syncthreads();
#pragma unroll
        for (int it = 0; it < 4; ++it) {
            const float4 a0 = *(const float4*)(aP[it]);
            const float4 a1 = *(const float4*)(aP[it] + 4);
            const float4 b0 = *(const float4*)(bP[it]);
            const float4 b1 = *(const float4*)(bP[it] + 4);
            uint4 ap, bp;
            ap.x = cvtpk(a0.x, a0.y); ap.y = cvtpk(a0.z, a0.w);
            ap.z = cvtpk(a1.x, a1.y); ap.w = cvtpk(a1.z, a1.w);
            bp.x = cvtpk(b0.x, b0.y); bp.y = cvtpk(b0.z, b0.w);
            bp.z = cvtpk(b1.x, b1.y); bp.w = cvtpk(b1.z, b1.w);
            *(uint4*)&As[slotv[it]] = ap;
            *(uint4*)&Bs[slotv[it]] = bp;
            aP[it] += 64;
            bP[it] += 64;
        }
        __syncthreads();
#pragma unroll
        for (int ks = 0; ks < 2; ++ks) {
            const int q = ks * 4 + quad;
            bf16x8 af[4], bfr[4];
#pragma unroll
            for (int mt = 0; mt < 4; ++mt) {
                const int m = wm + mt * 16 + l16;
                af[mt] = *(const bf16x8*)&As[m * 64 + ((q ^ (m & 7)) * 8)];
            }
#pragma unroll
            for (int nt = 0; nt < 4; ++nt) {
                const int n = wn + nt * 16 + l16;
                bfr[nt] = *(const bf16x8*)&Bs[n * 64 + ((q ^ (n & 7)) * 8)];
            }
#pragma unroll
            for (int mt = 0; mt < 4; ++mt)
#pragma unroll
                for (int nt = 0; nt < 4; ++nt)
                    acc[mt][nt] = __builtin_amdgcn_mfma_f32_16x16x32_bf16(
                        af[mt], bfr[nt], acc[mt][nt], 0, 0, 0);
        }
    }

    if (sub < 3) {
        unsigned short* GhB = Gh + ((size_t)b << 16);
        float* GdB = Gd + ((size_t)b << 12);
#pragma unroll
        for (int mt = 0; mt < 4; ++mt)
#pragma unroll
            for (int nt = 0; nt < 4; ++nt) {
                const int gcol = bn * 128 + wn + nt * 16 + l16;
#pragma unroll
                for (int r = 0; r < 4; ++r) {
                    const int grow = bm * 128 + wm + mt * 16 + quad * 4 + r;
                    const float v = ETA * acc[mt][nt][r];   // ETA folded here
                    GhB[(size_t)grow * 256 + gcol] = f2bf(v);
                    if ((grow >> 4) == (gcol >> 4))
                        GdB[((grow >> 4) << 8) + ((grow & 15) << 4) + (gcol & 15)] = v;
                }
            }
    } else {
        float* Pb = P0 + (size_t)b * NT * NOBS + (size_t)bm * 128 * NOBS;
#pragma unroll
        for (int mt = 0; mt < 4; ++mt)
#pragma unroll
            for (int nt = 0; nt < 4; ++nt)
#pragma unroll
                for (int r = 0; r < 4; ++r)
                    Pb[(size_t)(wm + mt * 16 + quad * 4 + r) * NOBS
                       + wn + nt * 16 + l16] = acc[mt][nt][r];
    }
}

// ---------------- K2: latency-optimized MFMA blocked scan ----------------
// EXACT round-4 restoration (~38us; passed at r4/r7/r8/r11). Pinned 37-42us
// across SIX structural variants (2-barrier, 1-barrier, rolled, pair-fused,
// single-wave spilled/unspilled) -> this is the session's empirical floor for
// the serial-scan stage; the per-step chain model (~8-13us) never matched and
// no variant beat this one. block = (b, 16 j's) -> 512 blocks (2/CU),
// 512 threads (8 waves). Serial scan has G rows software-pipelined 2 steps
// ahead into 3 rotating register row-buffers (the round-3 win: removed ~120cy
// LDS latency from the 256-step dependent chain). ETA pre-folded into G (k1).

#define LDROW(Q0, Q1, Q2, Q3, U1)                                          \
    {                                                                      \
        if ((U1) <= 14) {                                                  \
            if ((U1) <= 2)  Q0 = *(const f32x4*)(gdc + (U1) * 16);         \
            if ((U1) <= 6)  Q1 = *(const f32x4*)(gdc + (U1) * 16 + 4);     \
            if ((U1) <= 10) Q2 = *(const f32x4*)(gdc + (U1) * 16 + 8);     \
            Q3 = *(const f32x4*)(gdc + (U1) * 16 + 12);                    \
        }                                                                  \
    }

#define GV(Q0, Q1, Q2, Q3, V)                                              \
    ((V) < 4 ? (Q0)[(V) & 3] : (V) < 8 ? (Q1)[(V) & 3]                     \
             : (V) < 12 ? (Q2)[(V) & 3] : (Q3)[(V) & 3])

#define SCAN_STEP(U, C0, C1, C2, C3, N0, N1, N2, N3)                       \
    {                                                                      \
        LDROW(N0, N1, N2, N3, (U) + 2)                                     \
        const float y = __builtin_amdgcn_rcpf(1.f + __expf(-p[(U)]));      \
        ob[obOff + (size_t)((U) * NOBS)] = y;                              \
        _Pragma("unroll")                                                  \
        for (int v = (U) + 1; v < 16; ++v)                                 \
            p[v] = fmaf(y, GV(C0, C1, C2, C3, v), p[v]);                   \
        if ((U) & 1)                                                       \
            ybf2[cp * 128 + ((U) >> 1) * 16 + j] =                         \
                (unsigned)f2bf(eprev) | ((unsigned)f2bf(y) << 16);         \
        else                                                               \
            eprev = y;                                                     \
    }

__global__ __launch_bounds__(512, 4)
void k2_scan(const float* __restrict__ Gd, const unsigned short* __restrict__ Gh,
             const float* __restrict__ P0, float* __restrict__ out)
{
    __shared__ float gdiag[16 * 16 * 16];      // 16 KB [c][u][v] fp32 (= ETA*G)
    __shared__ float preS[16 * 17];            // padded transpose buffer
    __shared__ unsigned int ybf2[2 * 8 * 16];  // ping-pong packed y pairs

    const int tid  = threadIdx.x;
    const int lane = tid & 63;
    const int l16  = lane & 15;
    const int quad = lane >> 4;
    const int w    = __builtin_amdgcn_readfirstlane(tid >> 6);

    const int b  = blockIdx.x & 63;            // same-batch blocks -> same XCD
    const int jg = blockIdx.x >> 6;            // 0..7 col-groups of 16

    const float* Pb = P0 + (size_t)b * NT * NOBS + jg * 16;
    const unsigned short* GhB = Gh + ((size_t)b << 16);
    float* ob = out + (size_t)b * NT * NOBS + jg * 16;

    // stage fp32 diag tiles (Gd[b] is 16 KB contiguous).
    // chunk-0 tile (floats 0..255) is written by wave 0 itself (tids 0..63),
    // so the pre-loop scan only needs a wave-local lgkmcnt wait.
    {
        const f32x4* gs = (const f32x4*)(Gd + ((size_t)b << 12));
        ((f32x4*)gdiag)[tid]       = gs[tid];
        ((f32x4*)gdiag)[512 + tid] = gs[512 + tid];
    }

    // init pre C-fragments from P0: D[m=quad*4+r][n=l16]
    f32x4 acc[2];
#pragma unroll
    for (int s2 = 0; s2 < 2; ++s2)
#pragma unroll
        for (int r = 0; r < 4; ++r)
            acc[s2][r] = Pb[(size_t)(w * 32 + s2 * 16 + quad * 4 + r) * NOBS + l16];

    const int T0 = 2 * w, T1 = 2 * w + 1;

    union AB { bf16x8 v; unsigned int d[4]; };
    AB Acur0, Acur1, Anext0, Anext1;
#pragma unroll
    for (int p2 = 0; p2 < 4; ++p2) {
        Acur0.d[p2] = 0; Acur1.d[p2] = 0; Anext0.d[p2] = 0; Anext1.d[p2] = 0;
    }
    // prefetch A(T, c=0)
    if (quad < 2) {
        if (T0 > 0)
            Acur0.v = *(const bf16x8*)(GhB + (size_t)(T0 * 16 + l16) * 256 + quad * 8);
        Acur1.v = *(const bf16x8*)(GhB + (size_t)(T1 * 16 + l16) * 256 + quad * 8);
    }

    // dump one 16x16 fp32 tile through LDS, then 16 lanes run the serial
    // sigmoid scan for chunk c (intra-wave only: lgkmcnt wait, no barrier)
    auto scan_chunk = [&](const int c, const f32x4 a) {
#pragma unroll
        for (int r = 0; r < 4; ++r)
            preS[(quad * 4 + r) * 17 + l16] = a[r];
        asm volatile("s_waitcnt lgkmcnt(0)" ::: "memory");
        __builtin_amdgcn_s_setprio(1);
        if (lane < 16) {
            const int j = lane;
            const int cp = c & 1;
            const float* gdc = gdiag + (c << 8);
            const size_t obOff = (size_t)(c << 4) * NOBS + j;
            float p[16];
#pragma unroll
            for (int u = 0; u < 16; ++u) p[u] = preS[u * 17 + j];
            // 3 rotating row buffers, loads issued 2 steps ahead of use
            f32x4 Aq0, Aq1, Aq2, Aq3, Bq0, Bq1, Bq2, Bq3, Cq0, Cq1, Cq2, Cq3;
            LDROW(Aq0, Aq1, Aq2, Aq3, 0)
            LDROW(Bq0, Bq1, Bq2, Bq3, 1)
            float eprev = 0.f;
            SCAN_STEP(0,  Aq0, Aq1, Aq2, Aq3, Cq0, Cq1, Cq2, Cq3)
            SCAN_STEP(1,  Bq0, Bq1, Bq2, Bq3, Aq0, Aq1, Aq2, Aq3)
            SCAN_STEP(2,  Cq0, Cq1, Cq2, Cq3, Bq0, Bq1, Bq2, Bq3)
            SCAN_STEP(3,  Aq0, Aq1, Aq2, Aq3, Cq0, Cq1, Cq2, Cq3)
            SCAN_STEP(4,  Bq0, Bq1, Bq2, Bq3, Aq0, Aq1, Aq2, Aq3)
            SCAN_STEP(5,  Cq0, Cq1, Cq2, Cq3, Bq0, Bq1, Bq2, Bq3)
            SCAN_STEP(6,  Aq0, Aq1, Aq2, Aq3, Cq0, Cq1, Cq2, Cq3)
            SCAN_STEP(7,  Bq0, Bq1, Bq2, Bq3, Aq0, Aq1, Aq2, Aq3)
            SCAN_STEP(8,  Cq0, Cq1, Cq2, Cq3, Bq0, Bq1, Bq2, Bq3)
            SCAN_STEP(9,  Aq0, Aq1, Aq2, Aq3, Cq0, Cq1, Cq2, Cq3)
            SCAN_STEP(10, Bq0, Bq1, Bq2, Bq3, Aq0, Aq1, Aq2, Aq3)
            SCAN_STEP(11, Cq0, Cq1, Cq2, Cq3, Bq0, Bq1, Bq2, Bq3)
            SCAN_STEP(12, Aq0, Aq1, Aq2, Aq3, Cq0, Cq1, Cq2, Cq3)
            SCAN_STEP(13, Bq0, Bq1, Bq2, Bq3, Aq0, Aq1, Aq2, Aq3)
            SCAN_STEP(14, Cq0, Cq1, Cq2, Cq3, Bq0, Bq1, Bq2, Bq3)
            SCAN_STEP(15, Aq0, Aq1, Aq2, Aq3, Cq0, Cq1, Cq2, Cq3)
        }
        __builtin_amdgcn_s_setprio(0);
    };

    // chunk 0: owner = wave 0 (tile 0 is P0-only, no updates needed)
    if (w == 0)
        scan_chunk(0, acc[0]);
    __syncthreads();

#pragma unroll 1
    for (int c = 0; c < 15; ++c) {
        if (T1 > c) {   // wave still has live tiles
            // B fragment from ybf2[c&1]: B[k=u][n=j], upper K-half zero
            AB B;
#pragma unroll
            for (int p2 = 0; p2 < 4; ++p2) B.d[p2] = 0;
            if (quad < 2) {
#pragma unroll
                for (int p2 = 0; p2 < 4; ++p2)
                    B.d[p2] = ybf2[(c & 1) * 128 + (quad * 4 + p2) * 16 + l16];
            }
            // prefetch A(T, c+1) for next iteration (covered by MFMA+scan)
#pragma unroll
            for (int p2 = 0; p2 < 4; ++p2) { Anext0.d[p2] = 0; Anext1.d[p2] = 0; }
            if (quad < 2) {
                if (T0 > c + 1)
                    Anext0.v = *(const bf16x8*)(GhB + (size_t)(T0 * 16 + l16) * 256
                                                + (c + 1) * 16 + quad * 8);
                if (T1 > c + 1)
                    Anext1.v = *(const bf16x8*)(GhB + (size_t)(T1 * 16 + l16) * 256
                                                + (c + 1) * 16 + quad * 8);
            }
            // rank-16 updates of this wave's future tiles
            if (T0 > c)
                acc[0] = __builtin_amdgcn_mfma_f32_16x16x32_bf16(
                    Acur0.v, B.v, acc[0], 0, 0, 0);
            acc[1] = __builtin_amdgcn_mfma_f32_16x16x32_bf16(
                Acur1.v, B.v, acc[1], 0, 0, 0);
            // owner of chunk c+1 scans it now (its own tile is fully updated),
            // overlapping the other waves' update work until the barrier.
            // if/else keeps the acc[] index compile-time static (no scratch).
            if (w == ((c + 1) >> 1)) {
                if ((c + 1) & 1) scan_chunk(c + 1, acc[1]);
                else             scan_chunk(c + 1, acc[0]);
            }
            Acur0 = Anext0;
            Acur1 = Anext1;
        }
        __syncthreads();
    }
}

extern "C" void kernel_launch(void* const* d_in, const int* in_sizes, int n_in,
                              void* d_out, int out_size, void* d_ws, size_t ws_size,
                              hipStream_t stream)
{
    const float* X   = (const float*)d_in[0];
    const float* Wi  = (const float*)d_in[1];
    const int*   obs = (const int*)d_in[2];
    float*       out = (float*)d_out;

    float*          Gd = (float*)d_ws;                                  //  1 MB
    float*          P0 = (float*)((char*)d_ws + (1u << 20));            //  8 MB
    unsigned short* Gh = (unsigned short*)((char*)d_ws + (9u << 20));   //  8 MB

    hipLaunchKernelGGL(k1_gemm, dim3(NB * 5), dim3(256), 0, stream,
                       X, Wi, obs, Gd, Gh, P0);
    hipLaunchKernelGGL(k2_scan, dim3(NB * 8), dim3(512), 0, stream,
                       Gd, Gh, P0, out);
}